// Round 10
// baseline (99.670 us; speedup 1.0000x reference)
//
#include <hip/hip_runtime.h>
#include <hip/hip_bf16.h>
#include <math.h>

// Problem dims: B=64, S=T=128, D=1024, V=32000
// Output layout (fp32, concatenated):
//   src  @0          [64,128,1024]
//   satt @8388608    [64,128,1024]
//   at   @16777216   [64,128,128]
//   tgt  @17825792   [64,128,1024]
//   tatt @26214400   [64,128,1024]
//   ta   @34603008   [64,128,128]

#define NEG_INF -9999.0f

typedef __attribute__((ext_vector_type(8))) short   bf16x8;
typedef __attribute__((ext_vector_type(4))) float   f32x4;
typedef __attribute__((ext_vector_type(8))) unsigned short u16x8;

static __device__ inline ushort f2bf(float f) {
    union { float f; unsigned u; } v; v.f = f;
    unsigned r = v.u + 0x7fff + ((v.u >> 16) & 1);   // RNE
    return (ushort)(r >> 16);
}

// fp32 -> bf16 bits via HW cvt (RNE; compiler pairs into v_cvt_pk_bf16_f32)
static __device__ inline short fbs(float f) {
    union { __hip_bfloat16 h; short s; } u;
    u.h = __float2bfloat16(f);
    return u.s;
}

static __device__ inline bf16x8 pack8(float4 a, float4 b) {
    bf16x8 r;
    r[0] = fbs(a.x); r[1] = fbs(a.y); r[2] = fbs(a.z); r[3] = fbs(a.w);
    r[4] = fbs(b.x); r[5] = fbs(b.y); r[6] = fbs(b.z); r[7] = fbs(b.w);
    return r;
}

// XCD-aware bijective swizzle (nwg = 8*cpx).
static __device__ inline int xcd_swz(int bid, int cpx) {
    return (bid & 7) * cpx + (bid >> 3);
}

// ---------------------------------------------------------------------------
// K1: fused embedding gather + avgpool3 + residual -> fp32 out ONLY
// (eb/ebt eliminated; consumers convert from fp32). 64-pos tile + halo.
// Grid 2048: side(1) | b(6) | poshalf(1) | dchunk(3). 256 thr.
// ---------------------------------------------------------------------------
__global__ __launch_bounds__(256) void k_embed_all6(
    const int* __restrict__ ssent, const int* __restrict__ tsent,
    const float* __restrict__ stab, const float* __restrict__ ttab,
    float* __restrict__ srcO, float* __restrict__ tgtO)
{
    __shared__ float sm[66][136];            // 35.9 KB
    int blk = blockIdx.x;
    int side = blk >> 10;
    int rem = blk & 1023;
    int b = rem >> 4;
    int p0 = ((rem >> 3) & 1) << 6;          // 0 or 64
    int d0 = (rem & 7) << 7;
    const int*   sent  = side ? tsent : ssent;
    const float* table = side ? ttab  : stab;
    float* out = side ? tgtO : srcO;

    int tid = threadIdx.x;
    const int* ids = sent + b * 128;
    int pg = tid >> 5;                       // 0..7
    int c4 = (tid & 31) << 2;                // 0..124

    int myids[9];
#pragma unroll
    for (int i = 0; i < 9; ++i) {
        int row = pg + (i << 3);             // 0..71
        int pos = p0 + row - 1;
        pos = pos < 0 ? 0 : (pos > 127 ? 127 : pos);
        myids[i] = (row < 66) ? ids[pos] : 0;
    }

    // phase 1: independent gathers
#pragma unroll
    for (int i = 0; i < 9; ++i) {
        int row = pg + (i << 3);
        if (row < 66) {
            float4 v = *(const float4*)(table + (size_t)myids[i] * 1024 + d0 + c4);
            *(float4*)&sm[row][c4] = v;
        }
    }
    __syncthreads();

    // phase 2: pool + residual; write fp32 out
#pragma unroll
    for (int pp = 0; pp < 8; ++pp) {
        int pl = (pp << 3) + pg;             // 0..63
        int pos = p0 + pl;
        float4 c = *(const float4*)&sm[pl + 1][c4];
        float4 a = c;
        if (pos > 0) {
            float4 p = *(const float4*)&sm[pl][c4];
            a.x += p.x; a.y += p.y; a.z += p.z; a.w += p.w;
        }
        if (pos < 127) {
            float4 n = *(const float4*)&sm[pl + 2][c4];
            a.x += n.x; a.y += n.y; a.z += n.z; a.w += n.w;
        }
        float inv = (pos == 0 || pos == 127) ? 0.5f : (1.0f / 3.0f);
        float4 o;
        o.x = fmaf(a.x, inv, c.x); o.y = fmaf(a.y, inv, c.y);
        o.z = fmaf(a.z, inv, c.z); o.w = fmaf(a.w, inv, c.w);
        *(float4*)(out + (size_t)b * 131072 + (size_t)pos * 1024 + d0 + c4) = o;
    }
}

// ---------------------------------------------------------------------------
// K2: scores via MFMA from fp32 inputs (on-the-fly bf16 cvt), split-K x4,
// swapped operands -> D[s][t] f32x4 stores. 32x32 tile; grid B*16, swizzled.
// ---------------------------------------------------------------------------
__global__ __launch_bounds__(256) void k_scores_splitk2(
    const float* __restrict__ srcE, const float* __restrict__ tgtE,
    float* __restrict__ mul)
{
    __shared__ float red[3][64][17];
    int blk = xcd_swz(blockIdx.x, 128);
    int b = blk >> 4;
    int t0 = ((blk >> 2) & 3) * 32, s0 = (blk & 3) * 32;
    int tid = threadIdx.x;
    int w = tid >> 6, l = tid & 63;
    int rA = l & 15, kg = (l >> 4) << 3;
    int kbase = w << 8;                       // 0,256,512,768
    const float* sp = srcE + (size_t)b * 131072 + (size_t)(s0 + rA) * 1024 + kbase + kg;
    const float* tp = tgtE + (size_t)b * 131072 + (size_t)(t0 + rA) * 1024 + kbase + kg;
    f32x4 acc[2][2] = {};                     // [si][tj]
#pragma unroll 4
    for (int k0 = 0; k0 < 256; k0 += 32) {
        bf16x8 sf[2], tf[2];
#pragma unroll
        for (int i = 0; i < 2; ++i) {
            const float* pa = sp + (size_t)(i << 4) * 1024 + k0;
            sf[i] = pack8(*(const float4*)pa, *(const float4*)(pa + 4));
            const float* pb = tp + (size_t)(i << 4) * 1024 + k0;
            tf[i] = pack8(*(const float4*)pb, *(const float4*)(pb + 4));
        }
#pragma unroll
        for (int i = 0; i < 2; ++i)
#pragma unroll
            for (int j = 0; j < 2; ++j)
                acc[i][j] = __builtin_amdgcn_mfma_f32_16x16x32_bf16(
                    sf[i], tf[j], acc[i][j], 0, 0, 0);   // D rows=s, cols=t
    }
    if (w > 0) {
#pragma unroll
        for (int i = 0; i < 2; ++i)
#pragma unroll
            for (int j = 0; j < 2; ++j)
#pragma unroll
                for (int r = 0; r < 4; ++r)
                    red[w - 1][l][((i << 1) + j) * 4 + r] = acc[i][j][r];
    }
    __syncthreads();
    if (w == 0) {
#pragma unroll
        for (int i = 0; i < 2; ++i)
#pragma unroll
            for (int j = 0; j < 2; ++j)
#pragma unroll
                for (int r = 0; r < 4; ++r) {
                    int idx = ((i << 1) + j) * 4 + r;
                    acc[i][j][r] += red[0][l][idx] + red[1][l][idx] + red[2][l][idx];
                }
        float* mb = mul + (size_t)b * 16384;
        int cn = l & 15, sq = (l >> 4) << 2;
#pragma unroll
        for (int i = 0; i < 2; ++i)
#pragma unroll
            for (int j = 0; j < 2; ++j)
                *(f32x4*)(mb + (size_t)(t0 + (j << 4) + cn) * 128
                             + s0 + (i << 4) + sq) = acc[i][j];
    }
}

// ---------------------------------------------------------------------------
// K3: dual softmax, full occupancy. Block (b,i): row t=i AND col s=i.
// 8192 blocks x 64 thr, XCD-swizzled (cpx=1024).
// ---------------------------------------------------------------------------
__global__ __launch_bounds__(64) void k_softmax_dual(
    const float* __restrict__ mul, const int* __restrict__ ssent,
    const int* __restrict__ tsent, float* __restrict__ at,
    float* __restrict__ ta, ushort* __restrict__ pat, ushort* __restrict__ pta)
{
    int blk = xcd_swz(blockIdx.x, 1024);     // b*128 + i
    int b = blk >> 7, i = blk & 127;
    int lane = threadIdx.x;
    const float* mb = mul + (size_t)b * 16384;
    bool sv0 = ssent[b * 128 + lane] > 0, sv1 = ssent[b * 128 + lane + 64] > 0;
    bool tv0 = tsent[b * 128 + lane] > 0, tv1 = tsent[b * 128 + lane + 64] > 0;

    {   // row softmax: t=i over s -> ta[b,i,:]
        bool tm = tsent[b * 128 + i] > 0;
        float v0 = (tm && sv0) ? mb[i * 128 + lane] : NEG_INF;
        float v1 = (tm && sv1) ? mb[i * 128 + lane + 64] : NEG_INF;
        float m = fmaxf(v0, v1);
#pragma unroll
        for (int off = 32; off; off >>= 1) m = fmaxf(m, __shfl_xor(m, off));
        float e0 = __expf(v0 - m), e1 = __expf(v1 - m);
        float sum = e0 + e1;
#pragma unroll
        for (int off = 32; off; off >>= 1) sum += __shfl_xor(sum, off);
        float r = 1.0f / sum;
        float p0 = e0 * r, p1 = e1 * r;
        size_t o = (size_t)blk * 128;
        ta[o + lane] = p0; ta[o + lane + 64] = p1;
        pta[o + lane] = f2bf(p0); pta[o + lane + 64] = f2bf(p1);
    }
    {   // column softmax: s=i over t -> at[b,i,:]
        bool smk = ssent[b * 128 + i] > 0;
        float v0 = (smk && tv0) ? mb[lane * 128 + i] : NEG_INF;
        float v1 = (smk && tv1) ? mb[(lane + 64) * 128 + i] : NEG_INF;
        float m = fmaxf(v0, v1);
#pragma unroll
        for (int off = 32; off; off >>= 1) m = fmaxf(m, __shfl_xor(m, off));
        float e0 = __expf(v0 - m), e1 = __expf(v1 - m);
        float sum = e0 + e1;
#pragma unroll
        for (int off = 32; off; off >>= 1) sum += __shfl_xor(sum, off);
        float r = 1.0f / sum;
        float p0 = e0 * r, p1 = e1 * r;
        size_t o = (size_t)blk * 128;
        at[o + lane] = p0; at[o + lane + 64] = p1;
        pat[o + lane] = f2bf(p0); pat[o + lane + 64] = f2bf(p1);
    }
}

// ---------------------------------------------------------------------------
// K4: both attention matmuls, one launch. E staged from ROW-MAJOR fp32
// src/tgt with bf16 cvt during LDS write ([128 pos][44] ushort rows:
// b64-aligned writes, <=4-way-conflict column reads). 64(r) x 32(d) tile,
// 1 wave; grid 8192, XCD-swizzled. D[d][r] via swapped MFMA -> f32x4 stores.
// ---------------------------------------------------------------------------
__global__ __launch_bounds__(64) void k_attmm4(
    const ushort* __restrict__ pta, const float* __restrict__ srcE,
    float* __restrict__ satt,
    const ushort* __restrict__ pat, const float* __restrict__ tgtE,
    float* __restrict__ tatt)
{
    __shared__ ushort ldsE[128][44];         // 11 KB
    int blk = xcd_swz(blockIdx.x, 1024);
    int q = blk >> 12;
    int rem = blk & 4095;                    // b*64 + rt*32 + dt
    int b = rem >> 6;
    int rt = (rem >> 5) & 1, dt = rem & 31;
    const ushort* P = q ? pat : pta;
    const float* E = q ? tgtE : srcE;
    float* C = q ? tatt : satt;
    int r0 = rt << 6, d0 = dt << 5;
    int l = threadIdx.x;

    // stage E[0..127][d0..d0+31] fp32 -> bf16 ldsE (coalesced fp32 reads)
    {
        int pr = l >> 2, dd = (l & 3) << 3;
        const float* srcp = E + (size_t)b * 131072 + d0 + dd;
#pragma unroll
        for (int it = 0; it < 8; ++it) {
            int pos = (it << 4) + pr;
            float4 v0 = *(const float4*)(srcp + (size_t)pos * 1024);
            float4 v1 = *(const float4*)(srcp + (size_t)pos * 1024 + 4);
            u16x8 h;
            h[0] = (ushort)fbs(v0.x); h[1] = (ushort)fbs(v0.y);
            h[2] = (ushort)fbs(v0.z); h[3] = (ushort)fbs(v0.w);
            h[4] = (ushort)fbs(v1.x); h[5] = (ushort)fbs(v1.y);
            h[6] = (ushort)fbs(v1.z); h[7] = (ushort)fbs(v1.w);
            *(uint2*)&ldsE[pos][dd]     = *(const uint2*)&h;
            *(uint2*)&ldsE[pos][dd + 4] = *((const uint2*)&h + 1);
        }
    }
    __syncthreads();

    int rA = l & 15, kg = (l >> 4) << 3;
    const ushort* Pb = P + (size_t)b * 16384 + (size_t)(r0 + rA) * 128 + kg;
    f32x4 acc[4][2] = {};                    // [ri][dj]
#pragma unroll
    for (int k0 = 0; k0 < 128; k0 += 32) {
        bf16x8 pf[4], ef[2];
#pragma unroll
        for (int i = 0; i < 4; ++i)
            pf[i] = *(const bf16x8*)(Pb + (i << 4) * 128 + k0);
#pragma unroll
        for (int j = 0; j < 2; ++j) {
            int d = (j << 4) + rA;
#pragma unroll
            for (int kk = 0; kk < 8; ++kk)
                ef[j][kk] = (short)ldsE[k0 + kg + kk][d];
        }
#pragma unroll
        for (int i = 0; i < 4; ++i)
#pragma unroll
            for (int j = 0; j < 2; ++j)
                acc[i][j] = __builtin_amdgcn_mfma_f32_16x16x32_bf16(
                    ef[j], pf[i], acc[i][j], 0, 0, 0);   // D rows=d, cols=r
    }
    float* Cb = C + (size_t)b * 131072;
    int cn = l & 15, dq = (l >> 4) << 2;
#pragma unroll
    for (int i = 0; i < 4; ++i)
#pragma unroll
        for (int j = 0; j < 2; ++j)
            *(f32x4*)(Cb + (size_t)(r0 + (i << 4) + cn) * 1024
                         + d0 + (j << 4) + dq) = acc[i][j];
}

// ======================= fp32 fallback kernels (ws too small) ==============
__global__ __launch_bounds__(256) void k_embed_pool(
    const int* __restrict__ sent, const float* __restrict__ table,
    float* __restrict__ out)
{
    int blk = blockIdx.x;
    int b = blk >> 7, pos = blk & 127;
    const int* ids = sent + b * 128;
    int idc = ids[pos];
    int idp = (pos > 0)   ? ids[pos - 1] : -1;
    int idn = (pos < 127) ? ids[pos + 1] : -1;
    float inv = (pos == 0 || pos == 127) ? 0.5f : (1.0f / 3.0f);
    int d4 = threadIdx.x;
    float4 c = ((const float4*)(table + (size_t)idc * 1024))[d4];
    float4 a = c;
    if (idp >= 0) {
        float4 p = ((const float4*)(table + (size_t)idp * 1024))[d4];
        a.x += p.x; a.y += p.y; a.z += p.z; a.w += p.w;
    }
    if (idn >= 0) {
        float4 n = ((const float4*)(table + (size_t)idn * 1024))[d4];
        a.x += n.x; a.y += n.y; a.z += n.z; a.w += n.w;
    }
    float4 o;
    o.x = fmaf(a.x, inv, c.x); o.y = fmaf(a.y, inv, c.y);
    o.z = fmaf(a.z, inv, c.z); o.w = fmaf(a.w, inv, c.w);
    ((float4*)(out + (size_t)blk * 1024))[d4] = o;
}

__global__ __launch_bounds__(256) void k_scores(
    const float* __restrict__ srcE, const float* __restrict__ tgtE,
    float* __restrict__ mul)
{
    __shared__ float At[32][68];
    __shared__ float Bs[32][68];
    int b = blockIdx.y;
    int t0 = (blockIdx.x >> 1) * 64, s0 = (blockIdx.x & 1) * 64;
    const float* tg = tgtE + (size_t)b * 131072;
    const float* sr = srcE + (size_t)b * 131072;
    int tid = threadIdx.x, ty = tid >> 4, tx = tid & 15;
    float acc[4][4] = {};
    for (int k0 = 0; k0 < 1024; k0 += 32) {
        for (int q = tid; q < 512; q += 256) {
            int r = q >> 3, kc = (q & 7) << 2;
            float4 v = *(const float4*)(tg + (size_t)(t0 + r) * 1024 + k0 + kc);
            At[kc+0][r] = v.x; At[kc+1][r] = v.y; At[kc+2][r] = v.z; At[kc+3][r] = v.w;
            float4 w2 = *(const float4*)(sr + (size_t)(s0 + r) * 1024 + k0 + kc);
            Bs[kc+0][r] = w2.x; Bs[kc+1][r] = w2.y; Bs[kc+2][r] = w2.z; Bs[kc+3][r] = w2.w;
        }
        __syncthreads();
#pragma unroll 8
        for (int kk = 0; kk < 32; ++kk) {
            float4 av = *(const float4*)&At[kk][ty << 2];
            float4 bv = *(const float4*)&Bs[kk][tx << 2];
            float aa[4] = {av.x, av.y, av.z, av.w};
            float bb[4] = {bv.x, bv.y, bv.z, bv.w};
#pragma unroll
            for (int i = 0; i < 4; ++i)
#pragma unroll
                for (int j = 0; j < 4; ++j)
                    acc[i][j] = fmaf(aa[i], bb[j], acc[i][j]);
        }
        __syncthreads();
    }
    float* mb = mul + (size_t)b * 16384;
#pragma unroll
    for (int i = 0; i < 4; ++i)
        *(float4*)(mb + (size_t)(t0 + (ty << 2) + i) * 128 + s0 + (tx << 2)) =
            make_float4(acc[i][0], acc[i][1], acc[i][2], acc[i][3]);
}

__global__ __launch_bounds__(64) void k_softmax_at(
    const float* __restrict__ mul, const int* __restrict__ ssent,
    const int* __restrict__ tsent, float* __restrict__ at)
{
    int blk = blockIdx.x;
    int b = blk >> 7, s = blk & 127;
    int lane = threadIdx.x;
    bool smk = ssent[b * 128 + s] > 0;
    const float* mb = mul + (size_t)b * 16384;
    int t0 = lane, t1 = lane + 64;
    float v0 = (smk && tsent[b * 128 + t0] > 0) ? mb[(size_t)t0 * 128 + s] : NEG_INF;
    float v1 = (smk && tsent[b * 128 + t1] > 0) ? mb[(size_t)t1 * 128 + s] : NEG_INF;
    float m = fmaxf(v0, v1);
#pragma unroll
    for (int off = 32; off; off >>= 1) m = fmaxf(m, __shfl_xor(m, off));
    float e0 = __expf(v0 - m), e1 = __expf(v1 - m);
    float sum = e0 + e1;
#pragma unroll
    for (int off = 32; off; off >>= 1) sum += __shfl_xor(sum, off);
    float r = 1.0f / sum;
    float* ab = at + (size_t)blk * 128;
    ab[t0] = e0 * r; ab[t1] = e1 * r;
}

__global__ __launch_bounds__(64) void k_softmax_ta(
    float* __restrict__ mul, const int* __restrict__ ssent,
    const int* __restrict__ tsent)
{
    int blk = blockIdx.x;
    int b = blk >> 7, t = blk & 127;
    int lane = threadIdx.x;
    bool tm = tsent[b * 128 + t] > 0;
    float* mb = mul + (size_t)blk * 128;
    int s0 = lane, s1 = lane + 64;
    float v0 = (tm && ssent[b * 128 + s0] > 0) ? mb[s0] : NEG_INF;
    float v1 = (tm && ssent[b * 128 + s1] > 0) ? mb[s1] : NEG_INF;
    float m = fmaxf(v0, v1);
#pragma unroll
    for (int off = 32; off; off >>= 1) m = fmaxf(m, __shfl_xor(m, off));
    float e0 = __expf(v0 - m), e1 = __expf(v1 - m);
    float sum = e0 + e1;
#pragma unroll
    for (int off = 32; off; off >>= 1) sum += __shfl_xor(sum, off);
    float r = 1.0f / sum;
    mb[s0] = e0 * r; mb[s1] = e1 * r;
}

__global__ __launch_bounds__(256) void k_attmm(
    const float* __restrict__ P, const float* __restrict__ E,
    float* __restrict__ C)
{
    __shared__ float Pt[32][68];
    __shared__ float Et[32][68];
    int b = blockIdx.y;
    int r0 = (blockIdx.x >> 4) * 64, d0 = (blockIdx.x & 15) * 64;
    const float* Pb = P + (size_t)b * 16384;
    const float* Eb = E + (size_t)b * 131072;
    float* Cb = C + (size_t)b * 131072;
    int tid = threadIdx.x, ty = tid >> 4, tx = tid & 15;
    float acc[4][4] = {};
    for (int k0 = 0; k0 < 128; k0 += 32) {
        for (int q = tid; q < 512; q += 256) {
            int r = q >> 3, kc = (q & 7) << 2;
            float4 v = *(const float4*)(Pb + (size_t)(r0 + r) * 128 + k0 + kc);
            Pt[kc+0][r] = v.x; Pt[kc+1][r] = v.y; Pt[kc+2][r] = v.z; Pt[kc+3][r] = v.w;
            int kr = q >> 4, dc = (q & 15) << 2;
            *(float4*)&Et[kr][dc] = *(const float4*)(Eb + (size_t)(k0 + kr) * 1024 + d0 + dc);
        }
        __syncthreads();
#pragma unroll 8
        for (int kk = 0; kk < 32; ++kk) {
            float4 av = *(const float4*)&Pt[kk][ty << 2];
            float4 bv = *(const float4*)&Et[kk][tx << 2];
            float aa[4] = {av.x, av.y, av.z, av.w};
            float bb[4] = {bv.x, bv.y, bv.z, bv.w};
#pragma unroll
            for (int i = 0; i < 4; ++i)
#pragma unroll
                for (int j = 0; j < 4; ++j)
                    acc[i][j] = fmaf(aa[i], bb[j], acc[i][j]);
        }
        __syncthreads();
    }
#pragma unroll
    for (int i = 0; i < 4; ++i)
        *(float4*)(Cb + (size_t)(r0 + (ty << 2) + i) * 1024 + d0 + (tx << 2)) =
            make_float4(acc[i][0], acc[i][1], acc[i][2], acc[i][3]);
}

// ---------------------------------------------------------------------------
extern "C" void kernel_launch(void* const* d_in, const int* in_sizes, int n_in,
                              void* d_out, int out_size, void* d_ws, size_t ws_size,
                              hipStream_t stream)
{
    const int*   ssent = (const int*)d_in[0];
    const int*   tsent = (const int*)d_in[1];
    const float* stab  = (const float*)d_in[4];
    const float* ttab  = (const float*)d_in[5];
    float* out  = (float*)d_out;

    float* src  = out + 0;
    float* satt = out + 8388608;
    float* at   = out + 16777216;
    float* tgt  = out + 17825792;
    float* tatt = out + 26214400;
    float* ta   = out + 34603008;

    const size_t P_ELEMS = 1048576;      // 64*128*128
    const size_t WS_NEED = 2 * P_ELEMS * sizeof(ushort)
                         + P_ELEMS * sizeof(float);   // 8 MB

    if (ws_size >= WS_NEED) {
        ushort* pta  = (ushort*)d_ws;
        ushort* pat  = pta + P_ELEMS;
        float*  mulraw = (float*)(pat + P_ELEMS);

        k_embed_all6<<<2048, 256, 0, stream>>>(ssent, tsent, stab, ttab,
                                               src, tgt);
        k_scores_splitk2<<<1024, 256, 0, stream>>>(src, tgt, mulraw);
        k_softmax_dual<<<8192, 64, 0, stream>>>(mulraw, ssent, tsent,
                                                at, ta, pat, pta);
        k_attmm4<<<8192, 64, 0, stream>>>(pta, src, satt, pat, tgt, tatt);
    } else {
        // fp32 fallback
        k_embed_pool<<<8192, 256, 0, stream>>>(ssent, stab, src);
        k_embed_pool<<<8192, 256, 0, stream>>>(tsent, ttab, tgt);
        k_scores<<<dim3(4, 64), 256, 0, stream>>>(src, tgt, ta);
        k_softmax_at<<<8192, 64, 0, stream>>>(ta, ssent, tsent, at);
        k_softmax_ta<<<8192, 64, 0, stream>>>(ta, ssent, tsent);
        k_attmm<<<dim3(32, 64), 256, 0, stream>>>(ta, src, satt);
        k_attmm<<<dim3(32, 64), 256, 0, stream>>>(at, tgt, tatt);
    }
}

// Round 11
// 88.095 us; speedup vs baseline: 1.1314x; 1.1314x over previous
//
#include <hip/hip_runtime.h>
#include <math.h>

// Problem dims: B=64, S=T=128, D=1024, V=32000
// Output layout (fp32, concatenated):
//   src  @0          [64,128,1024]
//   satt @8388608    [64,128,1024]
//   at   @16777216   [64,128,128]
//   tgt  @17825792   [64,128,1024]
//   tatt @26214400   [64,128,1024]
//   ta   @34603008   [64,128,128]

#define NEG_INF -9999.0f

typedef __attribute__((ext_vector_type(8))) short   bf16x8;
typedef __attribute__((ext_vector_type(4))) float   f32x4;
typedef __attribute__((ext_vector_type(8))) unsigned short u16x8;

static __device__ inline ushort f2bf(float f) {
    union { float f; unsigned u; } v; v.f = f;
    unsigned r = v.u + 0x7fff + ((v.u >> 16) & 1);   // RNE
    return (ushort)(r >> 16);
}

// XCD-aware bijective swizzle (nwg = 8*cpx).
static __device__ inline int xcd_swz(int bid, int cpx) {
    return (bid & 7) * cpx + (bid >> 3);
}

// ---------------------------------------------------------------------------
// K1: fused embedding gather + avgpool3 + residual + bf16 row copy (eb).
// 64-pos tile + halo; 35.9KB LDS -> 4 blk/CU. Ids preloaded -> independent
// unrolled float4 gathers. Grid 2048: side|b|poshalf|dchunk. 256 thr.
// (R9-proven champion structure.)
// ---------------------------------------------------------------------------
__global__ __launch_bounds__(256) void k_embed_all5(
    const int* __restrict__ ssent, const int* __restrict__ tsent,
    const float* __restrict__ stab, const float* __restrict__ ttab,
    float* __restrict__ srcO, float* __restrict__ tgtO,
    ushort* __restrict__ ebS, ushort* __restrict__ ebT)
{
    __shared__ float sm[66][136];            // 35.9 KB
    int blk = blockIdx.x;
    int side = blk >> 10;
    int rem = blk & 1023;
    int b = rem >> 4;
    int p0 = ((rem >> 3) & 1) << 6;          // 0 or 64
    int d0 = (rem & 7) << 7;
    const int*   sent  = side ? tsent : ssent;
    const float* table = side ? ttab  : stab;
    float*  out = side ? tgtO : srcO;
    ushort* eb  = side ? ebT  : ebS;

    int tid = threadIdx.x;
    const int* ids = sent + b * 128;
    int pg = tid >> 5;                       // 0..7
    int c4 = (tid & 31) << 2;                // 0..124

    int myids[9];
#pragma unroll
    for (int i = 0; i < 9; ++i) {
        int row = pg + (i << 3);             // 0..71
        int pos = p0 + row - 1;
        pos = pos < 0 ? 0 : (pos > 127 ? 127 : pos);
        myids[i] = (row < 66) ? ids[pos] : 0;
    }

    // phase 1: independent gathers
#pragma unroll
    for (int i = 0; i < 9; ++i) {
        int row = pg + (i << 3);
        if (row < 66) {
            float4 v = *(const float4*)(table + (size_t)myids[i] * 1024 + d0 + c4);
            *(float4*)&sm[row][c4] = v;
        }
    }
    __syncthreads();

    // phase 2: pool + residual; write fp32 out + bf16 eb
#pragma unroll
    for (int pp = 0; pp < 8; ++pp) {
        int pl = (pp << 3) + pg;             // 0..63
        int pos = p0 + pl;
        float4 c = *(const float4*)&sm[pl + 1][c4];
        float4 a = c;
        if (pos > 0) {
            float4 p = *(const float4*)&sm[pl][c4];
            a.x += p.x; a.y += p.y; a.z += p.z; a.w += p.w;
        }
        if (pos < 127) {
            float4 n = *(const float4*)&sm[pl + 2][c4];
            a.x += n.x; a.y += n.y; a.z += n.z; a.w += n.w;
        }
        float inv = (pos == 0 || pos == 127) ? 0.5f : (1.0f / 3.0f);
        float4 o;
        o.x = fmaf(a.x, inv, c.x); o.y = fmaf(a.y, inv, c.y);
        o.z = fmaf(a.z, inv, c.z); o.w = fmaf(a.w, inv, c.w);
        size_t base = (size_t)b * 131072 + (size_t)pos * 1024 + d0 + c4;
        *(float4*)(out + base) = o;
        ushort4 h;
        h.x = f2bf(o.x); h.y = f2bf(o.y); h.z = f2bf(o.z); h.w = f2bf(o.w);
        *(ushort4*)(eb + base) = h;
    }
}

// ---------------------------------------------------------------------------
// K2: scores via MFMA, split-K x4, swapped operands -> D[s][t] f32x4 stores.
// 32x32 tile; grid = B*16, XCD-swizzled (cpx=128). Reads bf16 eb.
// ---------------------------------------------------------------------------
__global__ __launch_bounds__(256) void k_scores_splitk(
    const ushort* __restrict__ ebS, const ushort* __restrict__ ebT,
    float* __restrict__ mul)
{
    __shared__ float red[3][64][17];
    int blk = xcd_swz(blockIdx.x, 128);
    int b = blk >> 4;
    int t0 = ((blk >> 2) & 3) * 32, s0 = (blk & 3) * 32;
    int tid = threadIdx.x;
    int w = tid >> 6, l = tid & 63;
    int rA = l & 15, kg = (l >> 4) << 3;
    int kbase = w << 8;                       // 0,256,512,768
    const ushort* sp = ebS + (size_t)b * 131072 + (size_t)(s0 + rA) * 1024 + kbase + kg;
    const ushort* tp = ebT + (size_t)b * 131072 + (size_t)(t0 + rA) * 1024 + kbase + kg;
    f32x4 acc[2][2] = {};                     // [si][tj]
#pragma unroll 4
    for (int k0 = 0; k0 < 256; k0 += 32) {
        bf16x8 sf[2], tf[2];
#pragma unroll
        for (int i = 0; i < 2; ++i) {
            sf[i] = *(const bf16x8*)(sp + (size_t)(i << 4) * 1024 + k0);
            tf[i] = *(const bf16x8*)(tp + (size_t)(i << 4) * 1024 + k0);
        }
#pragma unroll
        for (int i = 0; i < 2; ++i)
#pragma unroll
            for (int j = 0; j < 2; ++j)
                acc[i][j] = __builtin_amdgcn_mfma_f32_16x16x32_bf16(
                    sf[i], tf[j], acc[i][j], 0, 0, 0);   // D rows=s, cols=t
    }
    if (w > 0) {
#pragma unroll
        for (int i = 0; i < 2; ++i)
#pragma unroll
            for (int j = 0; j < 2; ++j)
#pragma unroll
                for (int r = 0; r < 4; ++r)
                    red[w - 1][l][((i << 1) + j) * 4 + r] = acc[i][j][r];
    }
    __syncthreads();
    if (w == 0) {
#pragma unroll
        for (int i = 0; i < 2; ++i)
#pragma unroll
            for (int j = 0; j < 2; ++j)
#pragma unroll
                for (int r = 0; r < 4; ++r) {
                    int idx = ((i << 1) + j) * 4 + r;
                    acc[i][j][r] += red[0][l][idx] + red[1][l][idx] + red[2][l][idx];
                }
        float* mb = mul + (size_t)b * 16384;
        int cn = l & 15, sq = (l >> 4) << 2;
#pragma unroll
        for (int i = 0; i < 2; ++i)
#pragma unroll
            for (int j = 0; j < 2; ++j)
                *(f32x4*)(mb + (size_t)(t0 + (j << 4) + cn) * 128
                             + s0 + (i << 4) + sq) = acc[i][j];
    }
}

// ---------------------------------------------------------------------------
// K3: dual softmax, full occupancy. Block (b,i): row t=i AND col s=i.
// 8192 blocks x 64 thr, XCD-swizzled (cpx=1024).
// ---------------------------------------------------------------------------
__global__ __launch_bounds__(64) void k_softmax_dual(
    const float* __restrict__ mul, const int* __restrict__ ssent,
    const int* __restrict__ tsent, float* __restrict__ at,
    float* __restrict__ ta, ushort* __restrict__ pat, ushort* __restrict__ pta)
{
    int blk = xcd_swz(blockIdx.x, 1024);     // b*128 + i
    int b = blk >> 7, i = blk & 127;
    int lane = threadIdx.x;
    const float* mb = mul + (size_t)b * 16384;
    bool sv0 = ssent[b * 128 + lane] > 0, sv1 = ssent[b * 128 + lane + 64] > 0;
    bool tv0 = tsent[b * 128 + lane] > 0, tv1 = tsent[b * 128 + lane + 64] > 0;

    {   // row softmax: t=i over s -> ta[b,i,:]
        bool tm = tsent[b * 128 + i] > 0;
        float v0 = (tm && sv0) ? mb[i * 128 + lane] : NEG_INF;
        float v1 = (tm && sv1) ? mb[i * 128 + lane + 64] : NEG_INF;
        float m = fmaxf(v0, v1);
#pragma unroll
        for (int off = 32; off; off >>= 1) m = fmaxf(m, __shfl_xor(m, off));
        float e0 = __expf(v0 - m), e1 = __expf(v1 - m);
        float sum = e0 + e1;
#pragma unroll
        for (int off = 32; off; off >>= 1) sum += __shfl_xor(sum, off);
        float r = 1.0f / sum;
        float p0 = e0 * r, p1 = e1 * r;
        size_t o = (size_t)blk * 128;
        ta[o + lane] = p0; ta[o + lane + 64] = p1;
        pta[o + lane] = f2bf(p0); pta[o + lane + 64] = f2bf(p1);
    }
    {   // column softmax: s=i over t -> at[b,i,:]
        bool smk = ssent[b * 128 + i] > 0;
        float v0 = (smk && tv0) ? mb[lane * 128 + i] : NEG_INF;
        float v1 = (smk && tv1) ? mb[(lane + 64) * 128 + i] : NEG_INF;
        float m = fmaxf(v0, v1);
#pragma unroll
        for (int off = 32; off; off >>= 1) m = fmaxf(m, __shfl_xor(m, off));
        float e0 = __expf(v0 - m), e1 = __expf(v1 - m);
        float sum = e0 + e1;
#pragma unroll
        for (int off = 32; off; off >>= 1) sum += __shfl_xor(sum, off);
        float r = 1.0f / sum;
        float p0 = e0 * r, p1 = e1 * r;
        size_t o = (size_t)blk * 128;
        at[o + lane] = p0; at[o + lane + 64] = p1;
        pat[o + lane] = f2bf(p0); pat[o + lane + 64] = f2bf(p1);
    }
}

// ---------------------------------------------------------------------------
// K4: both attention matmuls, one launch. E staged from ROW-MAJOR bf16 eb
// into LDS [128 pos][46] (odd-dword row stride -> 4 disjoint bank octets ->
// conflict-free 2-way column reads; u32 staging writes for 4B alignment).
// First P fragment prefetched before staging. 64(r) x 32(d) tile, 1 wave;
// grid 8192, XCD-swizzled. D[d][r] via swapped MFMA -> f32x4 C-stores.
// ---------------------------------------------------------------------------
__global__ __launch_bounds__(64) void k_attmm3(
    const ushort* __restrict__ pta, const ushort* __restrict__ ebS,
    float* __restrict__ satt,
    const ushort* __restrict__ pat, const ushort* __restrict__ ebT,
    float* __restrict__ tatt)
{
    __shared__ ushort ldsE[128][46];         // 11.5 KB, 23-dword rows
    int blk = xcd_swz(blockIdx.x, 1024);
    int q = blk >> 12;
    int rem = blk & 4095;                    // b*64 + rt*32 + dt
    int b = rem >> 6;
    int rt = (rem >> 5) & 1, dt = rem & 31;
    const ushort* P = q ? pat : pta;
    const ushort* E = q ? ebT : ebS;
    float* C = q ? tatt : satt;
    int r0 = rt << 6, d0 = dt << 5;
    int l = threadIdx.x;
    int rA = l & 15, kg = (l >> 4) << 3;
    const ushort* Pb = P + (size_t)b * 16384 + (size_t)(r0 + rA) * 128 + kg;

    // prefetch k0=0 P fragments (overlaps E staging latency)
    bf16x8 pf0[4];
#pragma unroll
    for (int i = 0; i < 4; ++i)
        pf0[i] = *(const bf16x8*)(Pb + (i << 4) * 128);

    // stage E[0..127][d0..d0+31] -> ldsE (coalesced u16x8 global reads,
    // 4 x u32 LDS writes each)
    {
        int pr = l >> 2, dd = (l & 3) << 3;
        const ushort* srcp = E + (size_t)b * 131072 + d0 + dd;
#pragma unroll
        for (int it = 0; it < 8; ++it) {
            int pos = (it << 4) + pr;
            u16x8 v = *(const u16x8*)(srcp + (size_t)pos * 1024);
            const uint* vw = (const uint*)&v;
            uint* dst = (uint*)&ldsE[pos][dd];
            dst[0] = vw[0]; dst[1] = vw[1]; dst[2] = vw[2]; dst[3] = vw[3];
        }
    }
    __syncthreads();

    f32x4 acc[4][2] = {};                    // [ri][dj]
#pragma unroll
    for (int k0 = 0; k0 < 128; k0 += 32) {
        bf16x8 pf[4], ef[2];
        if (k0 == 0) {
#pragma unroll
            for (int i = 0; i < 4; ++i) pf[i] = pf0[i];
        } else {
#pragma unroll
            for (int i = 0; i < 4; ++i)
                pf[i] = *(const bf16x8*)(Pb + (i << 4) * 128 + k0);
        }
#pragma unroll
        for (int j = 0; j < 2; ++j) {
            int d = (j << 4) + rA;
#pragma unroll
            for (int kk = 0; kk < 8; ++kk)
                ef[j][kk] = (short)ldsE[k0 + kg + kk][d];
        }
#pragma unroll
        for (int i = 0; i < 4; ++i)
#pragma unroll
            for (int j = 0; j < 2; ++j)
                acc[i][j] = __builtin_amdgcn_mfma_f32_16x16x32_bf16(
                    ef[j], pf[i], acc[i][j], 0, 0, 0);   // D rows=d, cols=r
    }
    float* Cb = C + (size_t)b * 131072;
    int cn = l & 15, dq = (l >> 4) << 2;
#pragma unroll
    for (int i = 0; i < 4; ++i)
#pragma unroll
        for (int j = 0; j < 2; ++j)
            *(f32x4*)(Cb + (size_t)(r0 + (i << 4) + cn) * 1024
                         + d0 + (j << 4) + dq) = acc[i][j];
}

// ======================= fp32 fallback kernels (ws too small) ==============
__global__ __launch_bounds__(256) void k_embed_pool(
    const int* __restrict__ sent, const float* __restrict__ table,
    float* __restrict__ out)
{
    int blk = blockIdx.x;
    int b = blk >> 7, pos = blk & 127;
    const int* ids = sent + b * 128;
    int idc = ids[pos];
    int idp = (pos > 0)   ? ids[pos - 1] : -1;
    int idn = (pos < 127) ? ids[pos + 1] : -1;
    float inv = (pos == 0 || pos == 127) ? 0.5f : (1.0f / 3.0f);
    int d4 = threadIdx.x;
    float4 c = ((const float4*)(table + (size_t)idc * 1024))[d4];
    float4 a = c;
    if (idp >= 0) {
        float4 p = ((const float4*)(table + (size_t)idp * 1024))[d4];
        a.x += p.x; a.y += p.y; a.z += p.z; a.w += p.w;
    }
    if (idn >= 0) {
        float4 n = ((const float4*)(table + (size_t)idn * 1024))[d4];
        a.x += n.x; a.y += n.y; a.z += n.z; a.w += n.w;
    }
    float4 o;
    o.x = fmaf(a.x, inv, c.x); o.y = fmaf(a.y, inv, c.y);
    o.z = fmaf(a.z, inv, c.z); o.w = fmaf(a.w, inv, c.w);
    ((float4*)(out + (size_t)blk * 1024))[d4] = o;
}

__global__ __launch_bounds__(256) void k_scores(
    const float* __restrict__ srcE, const float* __restrict__ tgtE,
    float* __restrict__ mul)
{
    __shared__ float At[32][68];
    __shared__ float Bs[32][68];
    int b = blockIdx.y;
    int t0 = (blockIdx.x >> 1) * 64, s0 = (blockIdx.x & 1) * 64;
    const float* tg = tgtE + (size_t)b * 131072;
    const float* sr = srcE + (size_t)b * 131072;
    int tid = threadIdx.x, ty = tid >> 4, tx = tid & 15;
    float acc[4][4] = {};
    for (int k0 = 0; k0 < 1024; k0 += 32) {
        for (int q = tid; q < 512; q += 256) {
            int r = q >> 3, kc = (q & 7) << 2;
            float4 v = *(const float4*)(tg + (size_t)(t0 + r) * 1024 + k0 + kc);
            At[kc+0][r] = v.x; At[kc+1][r] = v.y; At[kc+2][r] = v.z; At[kc+3][r] = v.w;
            float4 w2 = *(const float4*)(sr + (size_t)(s0 + r) * 1024 + k0 + kc);
            Bs[kc+0][r] = w2.x; Bs[kc+1][r] = w2.y; Bs[kc+2][r] = w2.z; Bs[kc+3][r] = w2.w;
        }
        __syncthreads();
#pragma unroll 8
        for (int kk = 0; kk < 32; ++kk) {
            float4 av = *(const float4*)&At[kk][ty << 2];
            float4 bv = *(const float4*)&Bs[kk][tx << 2];
            float aa[4] = {av.x, av.y, av.z, av.w};
            float bb[4] = {bv.x, bv.y, bv.z, bv.w};
#pragma unroll
            for (int i = 0; i < 4; ++i)
#pragma unroll
                for (int j = 0; j < 4; ++j)
                    acc[i][j] = fmaf(aa[i], bb[j], acc[i][j]);
        }
        __syncthreads();
    }
    float* mb = mul + (size_t)b * 16384;
#pragma unroll
    for (int i = 0; i < 4; ++i)
        *(float4*)(mb + (size_t)(t0 + (ty << 2) + i) * 128 + s0 + (tx << 2)) =
            make_float4(acc[i][0], acc[i][1], acc[i][2], acc[i][3]);
}

__global__ __launch_bounds__(64) void k_softmax_at(
    const float* __restrict__ mul, const int* __restrict__ ssent,
    const int* __restrict__ tsent, float* __restrict__ at)
{
    int blk = blockIdx.x;
    int b = blk >> 7, s = blk & 127;
    int lane = threadIdx.x;
    bool smk = ssent[b * 128 + s] > 0;
    const float* mb = mul + (size_t)b * 16384;
    int t0 = lane, t1 = lane + 64;
    float v0 = (smk && tsent[b * 128 + t0] > 0) ? mb[(size_t)t0 * 128 + s] : NEG_INF;
    float v1 = (smk && tsent[b * 128 + t1] > 0) ? mb[(size_t)t1 * 128 + s] : NEG_INF;
    float m = fmaxf(v0, v1);
#pragma unroll
    for (int off = 32; off; off >>= 1) m = fmaxf(m, __shfl_xor(m, off));
    float e0 = __expf(v0 - m), e1 = __expf(v1 - m);
    float sum = e0 + e1;
#pragma unroll
    for (int off = 32; off; off >>= 1) sum += __shfl_xor(sum, off);
    float r = 1.0f / sum;
    float* ab = at + (size_t)blk * 128;
    ab[t0] = e0 * r; ab[t1] = e1 * r;
}

__global__ __launch_bounds__(64) void k_softmax_ta(
    float* __restrict__ mul, const int* __restrict__ ssent,
    const int* __restrict__ tsent)
{
    int blk = blockIdx.x;
    int b = blk >> 7, t = blk & 127;
    int lane = threadIdx.x;
    bool tm = tsent[b * 128 + t] > 0;
    float* mb = mul + (size_t)blk * 128;
    int s0 = lane, s1 = lane + 64;
    float v0 = (tm && ssent[b * 128 + s0] > 0) ? mb[s0] : NEG_INF;
    float v1 = (tm && ssent[b * 128 + s1] > 0) ? mb[s1] : NEG_INF;
    float m = fmaxf(v0, v1);
#pragma unroll
    for (int off = 32; off; off >>= 1) m = fmaxf(m, __shfl_xor(m, off));
    float e0 = __expf(v0 - m), e1 = __expf(v1 - m);
    float sum = e0 + e1;
#pragma unroll
    for (int off = 32; off; off >>= 1) sum += __shfl_xor(sum, off);
    float r = 1.0f / sum;
    mb[s0] = e0 * r; mb[s1] = e1 * r;
}

__global__ __launch_bounds__(256) void k_attmm(
    const float* __restrict__ P, const float* __restrict__ E,
    float* __restrict__ C)
{
    __shared__ float Pt[32][68];
    __shared__ float Et[32][68];
    int b = blockIdx.y;
    int r0 = (blockIdx.x >> 4) * 64, d0 = (blockIdx.x & 15) * 64;
    const float* Pb = P + (size_t)b * 16384;
    const float* Eb = E + (size_t)b * 131072;
    float* Cb = C + (size_t)b * 131072;
    int tid = threadIdx.x, ty = tid >> 4, tx = tid & 15;
    float acc[4][4] = {};
    for (int k0 = 0; k0 < 128; k0 += 32) {
        for (int q = tid; q < 512; q += 256) {
            int r = q >> 3, kc = (q & 7) << 2;
            float4 v = *(const float4*)(Pb + (size_t)(r0 + r) * 128 + k0 + kc);
            Pt[kc+0][r] = v.x; Pt[kc+1][r] = v.y; Pt[kc+2][r] = v.z; Pt[kc+3][r] = v.w;
            int kr = q >> 4, dc = (q & 15) << 2;
            *(float4*)&Et[kr][dc] = *(const float4*)(Eb + (size_t)(k0 + kr) * 1024 + d0 + dc);
        }
        __syncthreads();
#pragma unroll 8
        for (int kk = 0; kk < 32; ++kk) {
            float4 av = *(const float4*)&Pt[kk][ty << 2];
            float4 bv = *(const float4*)&Et[kk][tx << 2];
            float aa[4] = {av.x, av.y, av.z, av.w};
            float bb[4] = {bv.x, bv.y, bv.z, bv.w};
#pragma unroll
            for (int i = 0; i < 4; ++i)
#pragma unroll
                for (int j = 0; j < 4; ++j)
                    acc[i][j] = fmaf(aa[i], bb[j], acc[i][j]);
        }
        __syncthreads();
    }
#pragma unroll
    for (int i = 0; i < 4; ++i)
        *(float4*)(Cb + (size_t)(r0 + (ty << 2) + i) * 1024 + d0 + (tx << 2)) =
            make_float4(acc[i][0], acc[i][1], acc[i][2], acc[i][3]);
}

// ---------------------------------------------------------------------------
extern "C" void kernel_launch(void* const* d_in, const int* in_sizes, int n_in,
                              void* d_out, int out_size, void* d_ws, size_t ws_size,
                              hipStream_t stream)
{
    const int*   ssent = (const int*)d_in[0];
    const int*   tsent = (const int*)d_in[1];
    const float* stab  = (const float*)d_in[4];
    const float* ttab  = (const float*)d_in[5];
    float* out  = (float*)d_out;

    float* src  = out + 0;
    float* satt = out + 8388608;
    float* at   = out + 16777216;
    float* tgt  = out + 17825792;
    float* tatt = out + 26214400;
    float* ta   = out + 34603008;

    const size_t EB_ELEMS = 8388608;     // 64*128*1024
    const size_t P_ELEMS  = 1048576;     // 64*128*128
    const size_t WS_NEED  = (2 * EB_ELEMS + 2 * P_ELEMS) * sizeof(ushort)
                          + P_ELEMS * sizeof(float);   // ~41.9 MB

    if (ws_size >= WS_NEED) {
        ushort* ebS  = (ushort*)d_ws;
        ushort* ebT  = ebS  + EB_ELEMS;
        ushort* pta  = ebT  + EB_ELEMS;
        ushort* pat  = pta  + P_ELEMS;
        float*  mulraw = (float*)(pat + P_ELEMS);

        k_embed_all5<<<2048, 256, 0, stream>>>(ssent, tsent, stab, ttab,
                                               src, tgt, ebS, ebT);
        k_scores_splitk<<<1024, 256, 0, stream>>>(ebS, ebT, mulraw);
        k_softmax_dual<<<8192, 64, 0, stream>>>(mulraw, ssent, tsent,
                                                at, ta, pat, pta);
        k_attmm3<<<8192, 64, 0, stream>>>(pta, ebS, satt, pat, ebT, tatt);
    } else {
        // fp32 fallback
        k_embed_pool<<<8192, 256, 0, stream>>>(ssent, stab, src);
        k_embed_pool<<<8192, 256, 0, stream>>>(tsent, ttab, tgt);
        k_scores<<<dim3(4, 64), 256, 0, stream>>>(src, tgt, ta);
        k_softmax_at<<<8192, 64, 0, stream>>>(ta, ssent, tsent, at);
        k_softmax_ta<<<8192, 64, 0, stream>>>(ta, ssent, tsent);
        k_attmm<<<dim3(32, 64), 256, 0, stream>>>(ta, src, satt);
        k_attmm<<<dim3(32, 64), 256, 0, stream>>>(at, tgt, tatt);
    }
}

// Round 12
// 81.285 us; speedup vs baseline: 1.2262x; 1.0838x over previous
//
#include <hip/hip_runtime.h>
#include <math.h>

// Problem dims: B=64, S=T=128, D=1024, V=32000
// Output layout (fp32, concatenated):
//   src  @0          [64,128,1024]
//   satt @8388608    [64,128,1024]
//   at   @16777216   [64,128,128]
//   tgt  @17825792   [64,128,1024]
//   tatt @26214400   [64,128,1024]
//   ta   @34603008   [64,128,128]

#define NEG_INF -9999.0f

typedef __attribute__((ext_vector_type(8))) short   bf16x8;
typedef __attribute__((ext_vector_type(4))) float   f32x4;
typedef __attribute__((ext_vector_type(8))) unsigned short u16x8;

static __device__ inline ushort f2bf(float f) {
    union { float f; unsigned u; } v; v.f = f;
    unsigned r = v.u + 0x7fff + ((v.u >> 16) & 1);   // RNE
    return (ushort)(r >> 16);
}

// XCD-aware bijective swizzle (nwg = 8*cpx).
static __device__ inline int xcd_swz(int bid, int cpx) {
    return (bid & 7) * cpx + (bid >> 3);
}

// ---------------------------------------------------------------------------
// K1: fused embedding gather + avgpool3 + residual + bf16 row copy (eb).
// 64-pos tile + halo; 35.9KB LDS -> 4 blk/CU. Ids preloaded -> independent
// unrolled float4 gathers. Grid 2048: side|b|poshalf|dchunk. 256 thr.
// (R9-proven champion structure.)
// ---------------------------------------------------------------------------
__global__ __launch_bounds__(256) void k_embed_all5(
    const int* __restrict__ ssent, const int* __restrict__ tsent,
    const float* __restrict__ stab, const float* __restrict__ ttab,
    float* __restrict__ srcO, float* __restrict__ tgtO,
    ushort* __restrict__ ebS, ushort* __restrict__ ebT)
{
    __shared__ float sm[66][136];            // 35.9 KB
    int blk = blockIdx.x;
    int side = blk >> 10;
    int rem = blk & 1023;
    int b = rem >> 4;
    int p0 = ((rem >> 3) & 1) << 6;          // 0 or 64
    int d0 = (rem & 7) << 7;
    const int*   sent  = side ? tsent : ssent;
    const float* table = side ? ttab  : stab;
    float*  out = side ? tgtO : srcO;
    ushort* eb  = side ? ebT  : ebS;

    int tid = threadIdx.x;
    const int* ids = sent + b * 128;
    int pg = tid >> 5;                       // 0..7
    int c4 = (tid & 31) << 2;                // 0..124

    int myids[9];
#pragma unroll
    for (int i = 0; i < 9; ++i) {
        int row = pg + (i << 3);             // 0..71
        int pos = p0 + row - 1;
        pos = pos < 0 ? 0 : (pos > 127 ? 127 : pos);
        myids[i] = (row < 66) ? ids[pos] : 0;
    }

    // phase 1: independent gathers
#pragma unroll
    for (int i = 0; i < 9; ++i) {
        int row = pg + (i << 3);
        if (row < 66) {
            float4 v = *(const float4*)(table + (size_t)myids[i] * 1024 + d0 + c4);
            *(float4*)&sm[row][c4] = v;
        }
    }
    __syncthreads();

    // phase 2: pool + residual; write fp32 out + bf16 eb
#pragma unroll
    for (int pp = 0; pp < 8; ++pp) {
        int pl = (pp << 3) + pg;             // 0..63
        int pos = p0 + pl;
        float4 c = *(const float4*)&sm[pl + 1][c4];
        float4 a = c;
        if (pos > 0) {
            float4 p = *(const float4*)&sm[pl][c4];
            a.x += p.x; a.y += p.y; a.z += p.z; a.w += p.w;
        }
        if (pos < 127) {
            float4 n = *(const float4*)&sm[pl + 2][c4];
            a.x += n.x; a.y += n.y; a.z += n.z; a.w += n.w;
        }
        float inv = (pos == 0 || pos == 127) ? 0.5f : (1.0f / 3.0f);
        float4 o;
        o.x = fmaf(a.x, inv, c.x); o.y = fmaf(a.y, inv, c.y);
        o.z = fmaf(a.z, inv, c.z); o.w = fmaf(a.w, inv, c.w);
        size_t base = (size_t)b * 131072 + (size_t)pos * 1024 + d0 + c4;
        *(float4*)(out + base) = o;
        ushort4 h;
        h.x = f2bf(o.x); h.y = f2bf(o.y); h.z = f2bf(o.z); h.w = f2bf(o.w);
        *(ushort4*)(eb + base) = h;
    }
}

// ---------------------------------------------------------------------------
// K2: scores via MFMA, split-K x4, swapped operands -> D[s][t] f32x4 stores.
// 32x32 tile; grid = B*16, XCD-swizzled (cpx=128). Reads bf16 eb.
// ---------------------------------------------------------------------------
__global__ __launch_bounds__(256) void k_scores_splitk(
    const ushort* __restrict__ ebS, const ushort* __restrict__ ebT,
    float* __restrict__ mul)
{
    __shared__ float red[3][64][17];
    int blk = xcd_swz(blockIdx.x, 128);
    int b = blk >> 4;
    int t0 = ((blk >> 2) & 3) * 32, s0 = (blk & 3) * 32;
    int tid = threadIdx.x;
    int w = tid >> 6, l = tid & 63;
    int rA = l & 15, kg = (l >> 4) << 3;
    int kbase = w << 8;                       // 0,256,512,768
    const ushort* sp = ebS + (size_t)b * 131072 + (size_t)(s0 + rA) * 1024 + kbase + kg;
    const ushort* tp = ebT + (size_t)b * 131072 + (size_t)(t0 + rA) * 1024 + kbase + kg;
    f32x4 acc[2][2] = {};                     // [si][tj]
#pragma unroll 4
    for (int k0 = 0; k0 < 256; k0 += 32) {
        bf16x8 sf[2], tf[2];
#pragma unroll
        for (int i = 0; i < 2; ++i) {
            sf[i] = *(const bf16x8*)(sp + (size_t)(i << 4) * 1024 + k0);
            tf[i] = *(const bf16x8*)(tp + (size_t)(i << 4) * 1024 + k0);
        }
#pragma unroll
        for (int i = 0; i < 2; ++i)
#pragma unroll
            for (int j = 0; j < 2; ++j)
                acc[i][j] = __builtin_amdgcn_mfma_f32_16x16x32_bf16(
                    sf[i], tf[j], acc[i][j], 0, 0, 0);   // D rows=s, cols=t
    }
    if (w > 0) {
#pragma unroll
        for (int i = 0; i < 2; ++i)
#pragma unroll
            for (int j = 0; j < 2; ++j)
#pragma unroll
                for (int r = 0; r < 4; ++r)
                    red[w - 1][l][((i << 1) + j) * 4 + r] = acc[i][j][r];
    }
    __syncthreads();
    if (w == 0) {
#pragma unroll
        for (int i = 0; i < 2; ++i)
#pragma unroll
            for (int j = 0; j < 2; ++j)
#pragma unroll
                for (int r = 0; r < 4; ++r) {
                    int idx = ((i << 1) + j) * 4 + r;
                    acc[i][j][r] += red[0][l][idx] + red[1][l][idx] + red[2][l][idx];
                }
        float* mb = mul + (size_t)b * 16384;
        int cn = l & 15, sq = (l >> 4) << 2;
#pragma unroll
        for (int i = 0; i < 2; ++i)
#pragma unroll
            for (int j = 0; j < 2; ++j)
                *(f32x4*)(mb + (size_t)(t0 + (j << 4) + cn) * 128
                             + s0 + (i << 4) + sq) = acc[i][j];
    }
}

// ---------------------------------------------------------------------------
// K3: dual softmax, full occupancy. Block (b,i): row t=i AND col s=i.
// 8192 blocks x 64 thr, XCD-swizzled (cpx=1024).
// ---------------------------------------------------------------------------
__global__ __launch_bounds__(64) void k_softmax_dual(
    const float* __restrict__ mul, const int* __restrict__ ssent,
    const int* __restrict__ tsent, float* __restrict__ at,
    float* __restrict__ ta, ushort* __restrict__ pat, ushort* __restrict__ pta)
{
    int blk = xcd_swz(blockIdx.x, 1024);     // b*128 + i
    int b = blk >> 7, i = blk & 127;
    int lane = threadIdx.x;
    const float* mb = mul + (size_t)b * 16384;
    bool sv0 = ssent[b * 128 + lane] > 0, sv1 = ssent[b * 128 + lane + 64] > 0;
    bool tv0 = tsent[b * 128 + lane] > 0, tv1 = tsent[b * 128 + lane + 64] > 0;

    {   // row softmax: t=i over s -> ta[b,i,:]
        bool tm = tsent[b * 128 + i] > 0;
        float v0 = (tm && sv0) ? mb[i * 128 + lane] : NEG_INF;
        float v1 = (tm && sv1) ? mb[i * 128 + lane + 64] : NEG_INF;
        float m = fmaxf(v0, v1);
#pragma unroll
        for (int off = 32; off; off >>= 1) m = fmaxf(m, __shfl_xor(m, off));
        float e0 = __expf(v0 - m), e1 = __expf(v1 - m);
        float sum = e0 + e1;
#pragma unroll
        for (int off = 32; off; off >>= 1) sum += __shfl_xor(sum, off);
        float r = 1.0f / sum;
        float p0 = e0 * r, p1 = e1 * r;
        size_t o = (size_t)blk * 128;
        ta[o + lane] = p0; ta[o + lane + 64] = p1;
        pta[o + lane] = f2bf(p0); pta[o + lane + 64] = f2bf(p1);
    }
    {   // column softmax: s=i over t -> at[b,i,:]
        bool smk = ssent[b * 128 + i] > 0;
        float v0 = (smk && tv0) ? mb[lane * 128 + i] : NEG_INF;
        float v1 = (smk && tv1) ? mb[(lane + 64) * 128 + i] : NEG_INF;
        float m = fmaxf(v0, v1);
#pragma unroll
        for (int off = 32; off; off >>= 1) m = fmaxf(m, __shfl_xor(m, off));
        float e0 = __expf(v0 - m), e1 = __expf(v1 - m);
        float sum = e0 + e1;
#pragma unroll
        for (int off = 32; off; off >>= 1) sum += __shfl_xor(sum, off);
        float r = 1.0f / sum;
        float p0 = e0 * r, p1 = e1 * r;
        size_t o = (size_t)blk * 128;
        at[o + lane] = p0; at[o + lane + 64] = p1;
        pat[o + lane] = f2bf(p0); pat[o + lane + 64] = f2bf(p1);
    }
}

// ---------------------------------------------------------------------------
// K4: both attention matmuls, one launch. 128(r) x 64(d) tile, 4 waves
// (each 32r x 64d); grid 2048 -> eb staged ONCE per batch slice (halves
// logical L3 reads vs 64x32 tiles). LDS [128][66] (33-dword odd row stride:
// fragment-read lane-groups hit disjoint bank octets -> conflict-free;
// staging <=2-way = free). D[d][r] via swapped MFMA -> f32x4 C-stores.
// ---------------------------------------------------------------------------
__global__ __launch_bounds__(256) void k_attmm5(
    const ushort* __restrict__ pta, const ushort* __restrict__ ebS,
    float* __restrict__ satt,
    const ushort* __restrict__ pat, const ushort* __restrict__ ebT,
    float* __restrict__ tatt)
{
    __shared__ ushort ldsE[128][66];         // 16.9 KB
    int blk = xcd_swz(blockIdx.x, 256);      // 2048 = 8*256
    int q = blk >> 10;
    int rem = blk & 1023;                    // b*16 + dt
    int b = rem >> 4, dt = rem & 15;
    int d0 = dt << 6;
    const ushort* P = q ? pat : pta;
    const ushort* E = q ? ebT : ebS;
    float* C = q ? tatt : satt;
    int tid = threadIdx.x;
    int w = tid >> 6, l = tid & 63;

    // stage E[0..127][d0..d0+63] -> ldsE (contiguous 128B per 8-thread row)
    {
        int pr = tid >> 3, dd = (tid & 7) << 3;
        const ushort* srcp = E + (size_t)b * 131072 + d0 + dd;
#pragma unroll
        for (int it = 0; it < 4; ++it) {
            int pos = (it << 5) + pr;
            u16x8 v = *(const u16x8*)(srcp + (size_t)pos * 1024);
            const uint* vw = (const uint*)&v;
            uint* dst = (uint*)&ldsE[pos][dd];
            dst[0] = vw[0]; dst[1] = vw[1]; dst[2] = vw[2]; dst[3] = vw[3];
        }
    }
    __syncthreads();

    int rA = l & 15, kg = (l >> 4) << 3;
    int r0 = w << 5;                         // wave's 32 output rows
    const ushort* Pb = P + (size_t)b * 16384 + (size_t)(r0 + rA) * 128 + kg;
    f32x4 acc[2][4] = {};                    // [ri][dj]
#pragma unroll
    for (int k0 = 0; k0 < 128; k0 += 32) {
        bf16x8 pf[2], ef[4];
#pragma unroll
        for (int i = 0; i < 2; ++i)
            pf[i] = *(const bf16x8*)(Pb + (i << 4) * 128 + k0);
#pragma unroll
        for (int j = 0; j < 4; ++j) {
            int d = (j << 4) + rA;
#pragma unroll
            for (int kk = 0; kk < 8; ++kk)
                ef[j][kk] = (short)ldsE[k0 + kg + kk][d];
        }
#pragma unroll
        for (int i = 0; i < 2; ++i)
#pragma unroll
            for (int j = 0; j < 4; ++j)
                acc[i][j] = __builtin_amdgcn_mfma_f32_16x16x32_bf16(
                    ef[j], pf[i], acc[i][j], 0, 0, 0);   // D rows=d, cols=r
    }
    float* Cb = C + (size_t)b * 131072;
    int cn = l & 15, dq = (l >> 4) << 2;
#pragma unroll
    for (int i = 0; i < 2; ++i)
#pragma unroll
        for (int j = 0; j < 4; ++j)
            *(f32x4*)(Cb + (size_t)(r0 + (i << 4) + cn) * 1024
                         + d0 + (j << 4) + dq) = acc[i][j];
}

// ======================= fp32 fallback kernels (ws too small) ==============
__global__ __launch_bounds__(256) void k_embed_pool(
    const int* __restrict__ sent, const float* __restrict__ table,
    float* __restrict__ out)
{
    int blk = blockIdx.x;
    int b = blk >> 7, pos = blk & 127;
    const int* ids = sent + b * 128;
    int idc = ids[pos];
    int idp = (pos > 0)   ? ids[pos - 1] : -1;
    int idn = (pos < 127) ? ids[pos + 1] : -1;
    float inv = (pos == 0 || pos == 127) ? 0.5f : (1.0f / 3.0f);
    int d4 = threadIdx.x;
    float4 c = ((const float4*)(table + (size_t)idc * 1024))[d4];
    float4 a = c;
    if (idp >= 0) {
        float4 p = ((const float4*)(table + (size_t)idp * 1024))[d4];
        a.x += p.x; a.y += p.y; a.z += p.z; a.w += p.w;
    }
    if (idn >= 0) {
        float4 n = ((const float4*)(table + (size_t)idn * 1024))[d4];
        a.x += n.x; a.y += n.y; a.z += n.z; a.w += n.w;
    }
    float4 o;
    o.x = fmaf(a.x, inv, c.x); o.y = fmaf(a.y, inv, c.y);
    o.z = fmaf(a.z, inv, c.z); o.w = fmaf(a.w, inv, c.w);
    ((float4*)(out + (size_t)blk * 1024))[d4] = o;
}

__global__ __launch_bounds__(256) void k_scores(
    const float* __restrict__ srcE, const float* __restrict__ tgtE,
    float* __restrict__ mul)
{
    __shared__ float At[32][68];
    __shared__ float Bs[32][68];
    int b = blockIdx.y;
    int t0 = (blockIdx.x >> 1) * 64, s0 = (blockIdx.x & 1) * 64;
    const float* tg = tgtE + (size_t)b * 131072;
    const float* sr = srcE + (size_t)b * 131072;
    int tid = threadIdx.x, ty = tid >> 4, tx = tid & 15;
    float acc[4][4] = {};
    for (int k0 = 0; k0 < 1024; k0 += 32) {
        for (int q = tid; q < 512; q += 256) {
            int r = q >> 3, kc = (q & 7) << 2;
            float4 v = *(const float4*)(tg + (size_t)(t0 + r) * 1024 + k0 + kc);
            At[kc+0][r] = v.x; At[kc+1][r] = v.y; At[kc+2][r] = v.z; At[kc+3][r] = v.w;
            float4 w2 = *(const float4*)(sr + (size_t)(s0 + r) * 1024 + k0 + kc);
            Bs[kc+0][r] = w2.x; Bs[kc+1][r] = w2.y; Bs[kc+2][r] = w2.z; Bs[kc+3][r] = w2.w;
        }
        __syncthreads();
#pragma unroll 8
        for (int kk = 0; kk < 32; ++kk) {
            float4 av = *(const float4*)&At[kk][ty << 2];
            float4 bv = *(const float4*)&Bs[kk][tx << 2];
            float aa[4] = {av.x, av.y, av.z, av.w};
            float bb[4] = {bv.x, bv.y, bv.z, bv.w};
#pragma unroll
            for (int i = 0; i < 4; ++i)
#pragma unroll
                for (int j = 0; j < 4; ++j)
                    acc[i][j] = fmaf(aa[i], bb[j], acc[i][j]);
        }
        __syncthreads();
    }
    float* mb = mul + (size_t)b * 16384;
#pragma unroll
    for (int i = 0; i < 4; ++i)
        *(float4*)(mb + (size_t)(t0 + (ty << 2) + i) * 128 + s0 + (tx << 2)) =
            make_float4(acc[i][0], acc[i][1], acc[i][2], acc[i][3]);
}

__global__ __launch_bounds__(64) void k_softmax_at(
    const float* __restrict__ mul, const int* __restrict__ ssent,
    const int* __restrict__ tsent, float* __restrict__ at)
{
    int blk = blockIdx.x;
    int b = blk >> 7, s = blk & 127;
    int lane = threadIdx.x;
    bool smk = ssent[b * 128 + s] > 0;
    const float* mb = mul + (size_t)b * 16384;
    int t0 = lane, t1 = lane + 64;
    float v0 = (smk && tsent[b * 128 + t0] > 0) ? mb[(size_t)t0 * 128 + s] : NEG_INF;
    float v1 = (smk && tsent[b * 128 + t1] > 0) ? mb[(size_t)t1 * 128 + s] : NEG_INF;
    float m = fmaxf(v0, v1);
#pragma unroll
    for (int off = 32; off; off >>= 1) m = fmaxf(m, __shfl_xor(m, off));
    float e0 = __expf(v0 - m), e1 = __expf(v1 - m);
    float sum = e0 + e1;
#pragma unroll
    for (int off = 32; off; off >>= 1) sum += __shfl_xor(sum, off);
    float r = 1.0f / sum;
    float* ab = at + (size_t)blk * 128;
    ab[t0] = e0 * r; ab[t1] = e1 * r;
}

__global__ __launch_bounds__(64) void k_softmax_ta(
    float* __restrict__ mul, const int* __restrict__ ssent,
    const int* __restrict__ tsent)
{
    int blk = blockIdx.x;
    int b = blk >> 7, t = blk & 127;
    int lane = threadIdx.x;
    bool tm = tsent[b * 128 + t] > 0;
    float* mb = mul + (size_t)blk * 128;
    int s0 = lane, s1 = lane + 64;
    float v0 = (tm && ssent[b * 128 + s0] > 0) ? mb[s0] : NEG_INF;
    float v1 = (tm && ssent[b * 128 + s1] > 0) ? mb[s1] : NEG_INF;
    float m = fmaxf(v0, v1);
#pragma unroll
    for (int off = 32; off; off >>= 1) m = fmaxf(m, __shfl_xor(m, off));
    float e0 = __expf(v0 - m), e1 = __expf(v1 - m);
    float sum = e0 + e1;
#pragma unroll
    for (int off = 32; off; off >>= 1) sum += __shfl_xor(sum, off);
    float r = 1.0f / sum;
    mb[s0] = e0 * r; mb[s1] = e1 * r;
}

__global__ __launch_bounds__(256) void k_attmm(
    const float* __restrict__ P, const float* __restrict__ E,
    float* __restrict__ C)
{
    __shared__ float Pt[32][68];
    __shared__ float Et[32][68];
    int b = blockIdx.y;
    int r0 = (blockIdx.x >> 4) * 64, d0 = (blockIdx.x & 15) * 64;
    const float* Pb = P + (size_t)b * 16384;
    const float* Eb = E + (size_t)b * 131072;
    float* Cb = C + (size_t)b * 131072;
    int tid = threadIdx.x, ty = tid >> 4, tx = tid & 15;
    float acc[4][4] = {};
    for (int k0 = 0; k0 < 128; k0 += 32) {
        for (int q = tid; q < 512; q += 256) {
            int r = q >> 3, kc = (q & 7) << 2;
            float4 v = *(const float4*)(Pb + (size_t)(r0 + r) * 128 + k0 + kc);
            Pt[kc+0][r] = v.x; Pt[kc+1][r] = v.y; Pt[kc+2][r] = v.z; Pt[kc+3][r] = v.w;
            int kr = q >> 4, dc = (q & 15) << 2;
            *(float4*)&Et[kr][dc] = *(const float4*)(Eb + (size_t)(k0 + kr) * 1024 + d0 + dc);
        }
        __syncthreads();
#pragma unroll 8
        for (int kk = 0; kk < 32; ++kk) {
            float4 av = *(const float4*)&Pt[kk][ty << 2];
            float4 bv = *(const float4*)&Et[kk][tx << 2];
            float aa[4] = {av.x, av.y, av.z, av.w};
            float bb[4] = {bv.x, bv.y, bv.z, bv.w};
#pragma unroll
            for (int i = 0; i < 4; ++i)
#pragma unroll
                for (int j = 0; j < 4; ++j)
                    acc[i][j] = fmaf(aa[i], bb[j], acc[i][j]);
        }
        __syncthreads();
    }
#pragma unroll
    for (int i = 0; i < 4; ++i)
        *(float4*)(Cb + (size_t)(r0 + (ty << 2) + i) * 1024 + d0 + (tx << 2)) =
            make_float4(acc[i][0], acc[i][1], acc[i][2], acc[i][3]);
}

// ---------------------------------------------------------------------------
extern "C" void kernel_launch(void* const* d_in, const int* in_sizes, int n_in,
                              void* d_out, int out_size, void* d_ws, size_t ws_size,
                              hipStream_t stream)
{
    const int*   ssent = (const int*)d_in[0];
    const int*   tsent = (const int*)d_in[1];
    const float* stab  = (const float*)d_in[4];
    const float* ttab  = (const float*)d_in[5];
    float* out  = (float*)d_out;

    float* src  = out + 0;
    float* satt = out + 8388608;
    float* at   = out + 16777216;
    float* tgt  = out + 17825792;
    float* tatt = out + 26214400;
    float* ta   = out + 34603008;

    const size_t EB_ELEMS = 8388608;     // 64*128*1024
    const size_t P_ELEMS  = 1048576;     // 64*128*128
    const size_t WS_NEED  = (2 * EB_ELEMS + 2 * P_ELEMS) * sizeof(ushort)
                          + P_ELEMS * sizeof(float);   // ~41.9 MB

    if (ws_size >= WS_NEED) {
        ushort* ebS  = (ushort*)d_ws;
        ushort* ebT  = ebS  + EB_ELEMS;
        ushort* pta  = ebT  + EB_ELEMS;
        ushort* pat  = pta  + P_ELEMS;
        float*  mulraw = (float*)(pat + P_ELEMS);

        k_embed_all5<<<2048, 256, 0, stream>>>(ssent, tsent, stab, ttab,
                                               src, tgt, ebS, ebT);
        k_scores_splitk<<<1024, 256, 0, stream>>>(ebS, ebT, mulraw);
        k_softmax_dual<<<8192, 64, 0, stream>>>(mulraw, ssent, tsent,
                                                at, ta, pat, pta);
        k_attmm5<<<2048, 256, 0, stream>>>(pta, ebS, satt, pat, ebT, tatt);
    } else {
        // fp32 fallback
        k_embed_pool<<<8192, 256, 0, stream>>>(ssent, stab, src);
        k_embed_pool<<<8192, 256, 0, stream>>>(tsent, ttab, tgt);
        k_scores<<<dim3(4, 64), 256, 0, stream>>>(src, tgt, ta);
        k_softmax_at<<<8192, 64, 0, stream>>>(ta, ssent, tsent, at);
        k_softmax_ta<<<8192, 64, 0, stream>>>(ta, ssent, tsent);
        k_attmm<<<dim3(32, 64), 256, 0, stream>>>(ta, src, satt);
        k_attmm<<<dim3(32, 64), 256, 0, stream>>>(at, tgt, tatt);
    }
}

// Round 13
// 79.285 us; speedup vs baseline: 1.2571x; 1.0252x over previous
//
#include <hip/hip_runtime.h>
#include <math.h>

// Problem dims: B=64, S=T=128, D=1024, V=32000
// Output layout (fp32, concatenated):
//   src  @0          [64,128,1024]
//   satt @8388608    [64,128,1024]
//   at   @16777216   [64,128,128]
//   tgt  @17825792   [64,128,1024]
//   tatt @26214400   [64,128,1024]
//   ta   @34603008   [64,128,128]

#define NEG_INF -9999.0f

typedef __attribute__((ext_vector_type(8))) short   bf16x8;
typedef __attribute__((ext_vector_type(4))) float   f32x4;
typedef __attribute__((ext_vector_type(8))) unsigned short u16x8;

static __device__ inline ushort f2bf(float f) {
    union { float f; unsigned u; } v; v.f = f;
    unsigned r = v.u + 0x7fff + ((v.u >> 16) & 1);   // RNE
    return (ushort)(r >> 16);
}

// XCD-aware bijective swizzle (nwg = 8*cpx).
static __device__ inline int xcd_swz(int bid, int cpx) {
    return (bid & 7) * cpx + (bid >> 3);
}

// ---------------------------------------------------------------------------
// K1: fused embedding gather + avgpool3 + residual + bf16 row copy (eb).
// 64-pos tile + halo; 35.9KB LDS -> 4 blk/CU. Ids preloaded -> independent
// unrolled float4 gathers. Grid 2048: side|b|poshalf|dchunk. 256 thr.
// ---------------------------------------------------------------------------
__global__ __launch_bounds__(256) void k_embed_all5(
    const int* __restrict__ ssent, const int* __restrict__ tsent,
    const float* __restrict__ stab, const float* __restrict__ ttab,
    float* __restrict__ srcO, float* __restrict__ tgtO,
    ushort* __restrict__ ebS, ushort* __restrict__ ebT)
{
    __shared__ float sm[66][136];            // 35.9 KB
    int blk = blockIdx.x;
    int side = blk >> 10;
    int rem = blk & 1023;
    int b = rem >> 4;
    int p0 = ((rem >> 3) & 1) << 6;          // 0 or 64
    int d0 = (rem & 7) << 7;
    const int*   sent  = side ? tsent : ssent;
    const float* table = side ? ttab  : stab;
    float*  out = side ? tgtO : srcO;
    ushort* eb  = side ? ebT  : ebS;

    int tid = threadIdx.x;
    const int* ids = sent + b * 128;
    int pg = tid >> 5;                       // 0..7
    int c4 = (tid & 31) << 2;                // 0..124

    int myids[9];
#pragma unroll
    for (int i = 0; i < 9; ++i) {
        int row = pg + (i << 3);             // 0..71
        int pos = p0 + row - 1;
        pos = pos < 0 ? 0 : (pos > 127 ? 127 : pos);
        myids[i] = (row < 66) ? ids[pos] : 0;
    }

    // phase 1: independent gathers
#pragma unroll
    for (int i = 0; i < 9; ++i) {
        int row = pg + (i << 3);
        if (row < 66) {
            float4 v = *(const float4*)(table + (size_t)myids[i] * 1024 + d0 + c4);
            *(float4*)&sm[row][c4] = v;
        }
    }
    __syncthreads();

    // phase 2: pool + residual; write fp32 out + bf16 eb
#pragma unroll
    for (int pp = 0; pp < 8; ++pp) {
        int pl = (pp << 3) + pg;             // 0..63
        int pos = p0 + pl;
        float4 c = *(const float4*)&sm[pl + 1][c4];
        float4 a = c;
        if (pos > 0) {
            float4 p = *(const float4*)&sm[pl][c4];
            a.x += p.x; a.y += p.y; a.z += p.z; a.w += p.w;
        }
        if (pos < 127) {
            float4 n = *(const float4*)&sm[pl + 2][c4];
            a.x += n.x; a.y += n.y; a.z += n.z; a.w += n.w;
        }
        float inv = (pos == 0 || pos == 127) ? 0.5f : (1.0f / 3.0f);
        float4 o;
        o.x = fmaf(a.x, inv, c.x); o.y = fmaf(a.y, inv, c.y);
        o.z = fmaf(a.z, inv, c.z); o.w = fmaf(a.w, inv, c.w);
        size_t base = (size_t)b * 131072 + (size_t)pos * 1024 + d0 + c4;
        *(float4*)(out + base) = o;
        ushort4 h;
        h.x = f2bf(o.x); h.y = f2bf(o.y); h.z = f2bf(o.z); h.w = f2bf(o.w);
        *(ushort4*)(eb + base) = h;
    }
}

// ---------------------------------------------------------------------------
// K2: scores via MFMA, split-K x4, swapped operands -> D[s][t]. Writes BOTH
// mul[b][t][s] (f32x4) and mulT[b][s][t] (scalar, fire-and-forget) so both
// softmax passes read coalesced rows. 32x32 tile; grid B*16, XCD-swizzled.
// ---------------------------------------------------------------------------
__global__ __launch_bounds__(256) void k_scores_splitk(
    const ushort* __restrict__ ebS, const ushort* __restrict__ ebT,
    float* __restrict__ mul, float* __restrict__ mulT)
{
    __shared__ float red[3][64][17];
    int blk = xcd_swz(blockIdx.x, 128);
    int b = blk >> 4;
    int t0 = ((blk >> 2) & 3) * 32, s0 = (blk & 3) * 32;
    int tid = threadIdx.x;
    int w = tid >> 6, l = tid & 63;
    int rA = l & 15, kg = (l >> 4) << 3;
    int kbase = w << 8;                       // 0,256,512,768
    const ushort* sp = ebS + (size_t)b * 131072 + (size_t)(s0 + rA) * 1024 + kbase + kg;
    const ushort* tp = ebT + (size_t)b * 131072 + (size_t)(t0 + rA) * 1024 + kbase + kg;
    f32x4 acc[2][2] = {};                     // [si][tj]
#pragma unroll 4
    for (int k0 = 0; k0 < 256; k0 += 32) {
        bf16x8 sf[2], tf[2];
#pragma unroll
        for (int i = 0; i < 2; ++i) {
            sf[i] = *(const bf16x8*)(sp + (size_t)(i << 4) * 1024 + k0);
            tf[i] = *(const bf16x8*)(tp + (size_t)(i << 4) * 1024 + k0);
        }
#pragma unroll
        for (int i = 0; i < 2; ++i)
#pragma unroll
            for (int j = 0; j < 2; ++j)
                acc[i][j] = __builtin_amdgcn_mfma_f32_16x16x32_bf16(
                    sf[i], tf[j], acc[i][j], 0, 0, 0);   // D rows=s, cols=t
    }
    if (w > 0) {
#pragma unroll
        for (int i = 0; i < 2; ++i)
#pragma unroll
            for (int j = 0; j < 2; ++j)
#pragma unroll
                for (int r = 0; r < 4; ++r)
                    red[w - 1][l][((i << 1) + j) * 4 + r] = acc[i][j][r];
    }
    __syncthreads();
    if (w == 0) {
#pragma unroll
        for (int i = 0; i < 2; ++i)
#pragma unroll
            for (int j = 0; j < 2; ++j)
#pragma unroll
                for (int r = 0; r < 4; ++r) {
                    int idx = ((i << 1) + j) * 4 + r;
                    acc[i][j][r] += red[0][l][idx] + red[1][l][idx] + red[2][l][idx];
                }
        float* mb  = mul  + (size_t)b * 16384;
        float* mtb = mulT + (size_t)b * 16384;
        int cn = l & 15, sq = (l >> 4) << 2;
#pragma unroll
        for (int i = 0; i < 2; ++i)
#pragma unroll
            for (int j = 0; j < 2; ++j) {
                // mul[t][s]: f32x4 along s
                *(f32x4*)(mb + (size_t)(t0 + (j << 4) + cn) * 128
                             + s0 + (i << 4) + sq) = acc[i][j];
                // mulT[s][t]: scalar stores (4 rows s, same t)
#pragma unroll
                for (int r = 0; r < 4; ++r)
                    mtb[(size_t)(s0 + (i << 4) + sq + r) * 128
                        + t0 + (j << 4) + cn] = acc[i][j][r];
            }
    }
}

// ---------------------------------------------------------------------------
// K3: dual softmax, full occupancy, BOTH passes coalesced (col pass reads
// mulT). Block (b,i): row t=i from mul AND row s=i from mulT.
// 8192 blocks x 64 thr, XCD-swizzled (cpx=1024).
// ---------------------------------------------------------------------------
__global__ __launch_bounds__(64) void k_softmax_dual2(
    const float* __restrict__ mul, const float* __restrict__ mulT,
    const int* __restrict__ ssent, const int* __restrict__ tsent,
    float* __restrict__ at, float* __restrict__ ta,
    ushort* __restrict__ pat, ushort* __restrict__ pta)
{
    int blk = xcd_swz(blockIdx.x, 1024);     // b*128 + i
    int b = blk >> 7, i = blk & 127;
    int lane = threadIdx.x;
    bool sv0 = ssent[b * 128 + lane] > 0, sv1 = ssent[b * 128 + lane + 64] > 0;
    bool tv0 = tsent[b * 128 + lane] > 0, tv1 = tsent[b * 128 + lane + 64] > 0;

    {   // row softmax: t=i over s -> ta[b,i,:]
        const float* mb = mul + (size_t)b * 16384 + (size_t)i * 128;
        bool tm = tsent[b * 128 + i] > 0;
        float v0 = (tm && sv0) ? mb[lane] : NEG_INF;
        float v1 = (tm && sv1) ? mb[lane + 64] : NEG_INF;
        float m = fmaxf(v0, v1);
#pragma unroll
        for (int off = 32; off; off >>= 1) m = fmaxf(m, __shfl_xor(m, off));
        float e0 = __expf(v0 - m), e1 = __expf(v1 - m);
        float sum = e0 + e1;
#pragma unroll
        for (int off = 32; off; off >>= 1) sum += __shfl_xor(sum, off);
        float r = 1.0f / sum;
        float p0 = e0 * r, p1 = e1 * r;
        size_t o = (size_t)blk * 128;
        ta[o + lane] = p0; ta[o + lane + 64] = p1;
        pta[o + lane] = f2bf(p0); pta[o + lane + 64] = f2bf(p1);
    }
    {   // column softmax: s=i over t -> at[b,i,:]  (coalesced via mulT)
        const float* mtb = mulT + (size_t)b * 16384 + (size_t)i * 128;
        bool smk = ssent[b * 128 + i] > 0;
        float v0 = (smk && tv0) ? mtb[lane] : NEG_INF;
        float v1 = (smk && tv1) ? mtb[lane + 64] : NEG_INF;
        float m = fmaxf(v0, v1);
#pragma unroll
        for (int off = 32; off; off >>= 1) m = fmaxf(m, __shfl_xor(m, off));
        float e0 = __expf(v0 - m), e1 = __expf(v1 - m);
        float sum = e0 + e1;
#pragma unroll
        for (int off = 32; off; off >>= 1) sum += __shfl_xor(sum, off);
        float r = 1.0f / sum;
        float p0 = e0 * r, p1 = e1 * r;
        size_t o = (size_t)blk * 128;
        at[o + lane] = p0; at[o + lane + 64] = p1;
        pat[o + lane] = f2bf(p0); pat[o + lane + 64] = f2bf(p1);
    }
}

// ---------------------------------------------------------------------------
// K4: both attention matmuls, one launch. 128(r) x 64(d) tile, 4 waves
// (each 32r x 64d); grid 2048 -> eb staged ONCE per batch slice. LDS
// [128][66] (odd-dword stride -> conflict-free fragment reads). D[d][r]
// via swapped MFMA -> f32x4 C-stores. (R12-proven champion.)
// ---------------------------------------------------------------------------
__global__ __launch_bounds__(256) void k_attmm5(
    const ushort* __restrict__ pta, const ushort* __restrict__ ebS,
    float* __restrict__ satt,
    const ushort* __restrict__ pat, const ushort* __restrict__ ebT,
    float* __restrict__ tatt)
{
    __shared__ ushort ldsE[128][66];         // 16.9 KB
    int blk = xcd_swz(blockIdx.x, 256);      // 2048 = 8*256
    int q = blk >> 10;
    int rem = blk & 1023;                    // b*16 + dt
    int b = rem >> 4, dt = rem & 15;
    int d0 = dt << 6;
    const ushort* P = q ? pat : pta;
    const ushort* E = q ? ebT : ebS;
    float* C = q ? tatt : satt;
    int tid = threadIdx.x;
    int w = tid >> 6, l = tid & 63;

    // stage E[0..127][d0..d0+63] -> ldsE
    {
        int pr = tid >> 3, dd = (tid & 7) << 3;
        const ushort* srcp = E + (size_t)b * 131072 + d0 + dd;
#pragma unroll
        for (int it = 0; it < 4; ++it) {
            int pos = (it << 5) + pr;
            u16x8 v = *(const u16x8*)(srcp + (size_t)pos * 1024);
            const uint* vw = (const uint*)&v;
            uint* dst = (uint*)&ldsE[pos][dd];
            dst[0] = vw[0]; dst[1] = vw[1]; dst[2] = vw[2]; dst[3] = vw[3];
        }
    }
    __syncthreads();

    int rA = l & 15, kg = (l >> 4) << 3;
    int r0 = w << 5;                         // wave's 32 output rows
    const ushort* Pb = P + (size_t)b * 16384 + (size_t)(r0 + rA) * 128 + kg;
    f32x4 acc[2][4] = {};                    // [ri][dj]
#pragma unroll
    for (int k0 = 0; k0 < 128; k0 += 32) {
        bf16x8 pf[2], ef[4];
#pragma unroll
        for (int i = 0; i < 2; ++i)
            pf[i] = *(const bf16x8*)(Pb + (i << 4) * 128 + k0);
#pragma unroll
        for (int j = 0; j < 4; ++j) {
            int d = (j << 4) + rA;
#pragma unroll
            for (int kk = 0; kk < 8; ++kk)
                ef[j][kk] = (short)ldsE[k0 + kg + kk][d];
        }
#pragma unroll
        for (int i = 0; i < 2; ++i)
#pragma unroll
            for (int j = 0; j < 4; ++j)
                acc[i][j] = __builtin_amdgcn_mfma_f32_16x16x32_bf16(
                    ef[j], pf[i], acc[i][j], 0, 0, 0);   // D rows=d, cols=r
    }
    float* Cb = C + (size_t)b * 131072;
    int cn = l & 15, dq = (l >> 4) << 2;
#pragma unroll
    for (int i = 0; i < 2; ++i)
#pragma unroll
        for (int j = 0; j < 4; ++j)
            *(f32x4*)(Cb + (size_t)(r0 + (i << 4) + cn) * 1024
                         + d0 + (j << 4) + dq) = acc[i][j];
}

// ======================= fp32 fallback kernels (ws too small) ==============
__global__ __launch_bounds__(256) void k_embed_pool(
    const int* __restrict__ sent, const float* __restrict__ table,
    float* __restrict__ out)
{
    int blk = blockIdx.x;
    int b = blk >> 7, pos = blk & 127;
    const int* ids = sent + b * 128;
    int idc = ids[pos];
    int idp = (pos > 0)   ? ids[pos - 1] : -1;
    int idn = (pos < 127) ? ids[pos + 1] : -1;
    float inv = (pos == 0 || pos == 127) ? 0.5f : (1.0f / 3.0f);
    int d4 = threadIdx.x;
    float4 c = ((const float4*)(table + (size_t)idc * 1024))[d4];
    float4 a = c;
    if (idp >= 0) {
        float4 p = ((const float4*)(table + (size_t)idp * 1024))[d4];
        a.x += p.x; a.y += p.y; a.z += p.z; a.w += p.w;
    }
    if (idn >= 0) {
        float4 n = ((const float4*)(table + (size_t)idn * 1024))[d4];
        a.x += n.x; a.y += n.y; a.z += n.z; a.w += n.w;
    }
    float4 o;
    o.x = fmaf(a.x, inv, c.x); o.y = fmaf(a.y, inv, c.y);
    o.z = fmaf(a.z, inv, c.z); o.w = fmaf(a.w, inv, c.w);
    ((float4*)(out + (size_t)blk * 1024))[d4] = o;
}

__global__ __launch_bounds__(256) void k_scores(
    const float* __restrict__ srcE, const float* __restrict__ tgtE,
    float* __restrict__ mul)
{
    __shared__ float At[32][68];
    __shared__ float Bs[32][68];
    int b = blockIdx.y;
    int t0 = (blockIdx.x >> 1) * 64, s0 = (blockIdx.x & 1) * 64;
    const float* tg = tgtE + (size_t)b * 131072;
    const float* sr = srcE + (size_t)b * 131072;
    int tid = threadIdx.x, ty = tid >> 4, tx = tid & 15;
    float acc[4][4] = {};
    for (int k0 = 0; k0 < 1024; k0 += 32) {
        for (int q = tid; q < 512; q += 256) {
            int r = q >> 3, kc = (q & 7) << 2;
            float4 v = *(const float4*)(tg + (size_t)(t0 + r) * 1024 + k0 + kc);
            At[kc+0][r] = v.x; At[kc+1][r] = v.y; At[kc+2][r] = v.z; At[kc+3][r] = v.w;
            float4 w2 = *(const float4*)(sr + (size_t)(s0 + r) * 1024 + k0 + kc);
            Bs[kc+0][r] = w2.x; Bs[kc+1][r] = w2.y; Bs[kc+2][r] = w2.z; Bs[kc+3][r] = w2.w;
        }
        __syncthreads();
#pragma unroll 8
        for (int kk = 0; kk < 32; ++kk) {
            float4 av = *(const float4*)&At[kk][ty << 2];
            float4 bv = *(const float4*)&Bs[kk][tx << 2];
            float aa[4] = {av.x, av.y, av.z, av.w};
            float bb[4] = {bv.x, bv.y, bv.z, bv.w};
#pragma unroll
            for (int i = 0; i < 4; ++i)
#pragma unroll
                for (int j = 0; j < 4; ++j)
                    acc[i][j] = fmaf(aa[i], bb[j], acc[i][j]);
        }
        __syncthreads();
    }
    float* mb = mul + (size_t)b * 16384;
#pragma unroll
    for (int i = 0; i < 4; ++i)
        *(float4*)(mb + (size_t)(t0 + (ty << 2) + i) * 128 + s0 + (tx << 2)) =
            make_float4(acc[i][0], acc[i][1], acc[i][2], acc[i][3]);
}

__global__ __launch_bounds__(64) void k_softmax_at(
    const float* __restrict__ mul, const int* __restrict__ ssent,
    const int* __restrict__ tsent, float* __restrict__ at)
{
    int blk = blockIdx.x;
    int b = blk >> 7, s = blk & 127;
    int lane = threadIdx.x;
    bool smk = ssent[b * 128 + s] > 0;
    const float* mb = mul + (size_t)b * 16384;
    int t0 = lane, t1 = lane + 64;
    float v0 = (smk && tsent[b * 128 + t0] > 0) ? mb[(size_t)t0 * 128 + s] : NEG_INF;
    float v1 = (smk && tsent[b * 128 + t1] > 0) ? mb[(size_t)t1 * 128 + s] : NEG_INF;
    float m = fmaxf(v0, v1);
#pragma unroll
    for (int off = 32; off; off >>= 1) m = fmaxf(m, __shfl_xor(m, off));
    float e0 = __expf(v0 - m), e1 = __expf(v1 - m);
    float sum = e0 + e1;
#pragma unroll
    for (int off = 32; off; off >>= 1) sum += __shfl_xor(sum, off);
    float r = 1.0f / sum;
    float* ab = at + (size_t)blk * 128;
    ab[t0] = e0 * r; ab[t1] = e1 * r;
}

__global__ __launch_bounds__(64) void k_softmax_ta(
    float* __restrict__ mul, const int* __restrict__ ssent,
    const int* __restrict__ tsent)
{
    int blk = blockIdx.x;
    int b = blk >> 7, t = blk & 127;
    int lane = threadIdx.x;
    bool tm = tsent[b * 128 + t] > 0;
    float* mb = mul + (size_t)blk * 128;
    int s0 = lane, s1 = lane + 64;
    float v0 = (tm && ssent[b * 128 + s0] > 0) ? mb[s0] : NEG_INF;
    float v1 = (tm && ssent[b * 128 + s1] > 0) ? mb[s1] : NEG_INF;
    float m = fmaxf(v0, v1);
#pragma unroll
    for (int off = 32; off; off >>= 1) m = fmaxf(m, __shfl_xor(m, off));
    float e0 = __expf(v0 - m), e1 = __expf(v1 - m);
    float sum = e0 + e1;
#pragma unroll
    for (int off = 32; off; off >>= 1) sum += __shfl_xor(sum, off);
    float r = 1.0f / sum;
    mb[s0] = e0 * r; mb[s1] = e1 * r;
}

__global__ __launch_bounds__(256) void k_attmm(
    const float* __restrict__ P, const float* __restrict__ E,
    float* __restrict__ C)
{
    __shared__ float Pt[32][68];
    __shared__ float Et[32][68];
    int b = blockIdx.y;
    int r0 = (blockIdx.x >> 4) * 64, d0 = (blockIdx.x & 15) * 64;
    const float* Pb = P + (size_t)b * 16384;
    const float* Eb = E + (size_t)b * 131072;
    float* Cb = C + (size_t)b * 131072;
    int tid = threadIdx.x, ty = tid >> 4, tx = tid & 15;
    float acc[4][4] = {};
    for (int k0 = 0; k0 < 128; k0 += 32) {
        for (int q = tid; q < 512; q += 256) {
            int r = q >> 3, kc = (q & 7) << 2;
            float4 v = *(const float4*)(Pb + (size_t)(r0 + r) * 128 + k0 + kc);
            Pt[kc+0][r] = v.x; Pt[kc+1][r] = v.y; Pt[kc+2][r] = v.z; Pt[kc+3][r] = v.w;
            int kr = q >> 4, dc = (q & 15) << 2;
            *(float4*)&Et[kr][dc] = *(const float4*)(Eb + (size_t)(k0 + kr) * 1024 + d0 + dc);
        }
        __syncthreads();
#pragma unroll 8
        for (int kk = 0; kk < 32; ++kk) {
            float4 av = *(const float4*)&Pt[kk][ty << 2];
            float4 bv = *(const float4*)&Et[kk][tx << 2];
            float aa[4] = {av.x, av.y, av.z, av.w};
            float bb[4] = {bv.x, bv.y, bv.z, bv.w};
#pragma unroll
            for (int i = 0; i < 4; ++i)
#pragma unroll
                for (int j = 0; j < 4; ++j)
                    acc[i][j] = fmaf(aa[i], bb[j], acc[i][j]);
        }
        __syncthreads();
    }
#pragma unroll
    for (int i = 0; i < 4; ++i)
        *(float4*)(Cb + (size_t)(r0 + (ty << 2) + i) * 1024 + d0 + (tx << 2)) =
            make_float4(acc[i][0], acc[i][1], acc[i][2], acc[i][3]);
}

// ---------------------------------------------------------------------------
extern "C" void kernel_launch(void* const* d_in, const int* in_sizes, int n_in,
                              void* d_out, int out_size, void* d_ws, size_t ws_size,
                              hipStream_t stream)
{
    const int*   ssent = (const int*)d_in[0];
    const int*   tsent = (const int*)d_in[1];
    const float* stab  = (const float*)d_in[4];
    const float* ttab  = (const float*)d_in[5];
    float* out  = (float*)d_out;

    float* src  = out + 0;
    float* satt = out + 8388608;
    float* at   = out + 16777216;
    float* tgt  = out + 17825792;
    float* tatt = out + 26214400;
    float* ta   = out + 34603008;

    const size_t EB_ELEMS = 8388608;     // 64*128*1024
    const size_t P_ELEMS  = 1048576;     // 64*128*128
    const size_t WS_NEED  = (2 * EB_ELEMS + 2 * P_ELEMS) * sizeof(ushort)
                          + 2 * P_ELEMS * sizeof(float);   // ~46 MB

    if (ws_size >= WS_NEED) {
        ushort* ebS  = (ushort*)d_ws;
        ushort* ebT  = ebS  + EB_ELEMS;
        ushort* pta  = ebT  + EB_ELEMS;
        ushort* pat  = pta  + P_ELEMS;
        float*  mulraw = (float*)(pat + P_ELEMS);
        float*  mulT   = mulraw + P_ELEMS;

        k_embed_all5<<<2048, 256, 0, stream>>>(ssent, tsent, stab, ttab,
                                               src, tgt, ebS, ebT);
        k_scores_splitk<<<1024, 256, 0, stream>>>(ebS, ebT, mulraw, mulT);
        k_softmax_dual2<<<8192, 64, 0, stream>>>(mulraw, mulT, ssent, tsent,
                                                 at, ta, pat, pta);
        k_attmm5<<<2048, 256, 0, stream>>>(pta, ebS, satt, pat, ebT, tatt);
    } else {
        // fp32 fallback
        k_embed_pool<<<8192, 256, 0, stream>>>(ssent, stab, src);
        k_embed_pool<<<8192, 256, 0, stream>>>(tsent, ttab, tgt);
        k_scores<<<dim3(4, 64), 256, 0, stream>>>(src, tgt, ta);
        k_softmax_at<<<8192, 64, 0, stream>>>(ta, ssent, tsent, at);
        k_softmax_ta<<<8192, 64, 0, stream>>>(ta, ssent, tsent);
        k_attmm<<<dim3(32, 64), 256, 0, stream>>>(ta, src, satt);
        k_attmm<<<dim3(32, 64), 256, 0, stream>>>(at, tgt, tatt);
    }
}